// Round 11
// baseline (74.778 us; speedup 1.0000x reference)
//
#include <hip/hip_runtime.h>

// CRF forward partition via ergodic chunked scan — MFMA formulation.
// B=256, T=1024, K=50. Wave = 16 batches x one chunk (S=8 steps + H=6 halo).
// Per step, 8x mfma_f32_16x16x32_bf16 compute S = X·E for 16 batches.
//
// R11 changes vs R10 (schedule-only; data path byte-identical):
//  * SCHUNK 16->8: steps/wave 22->14, waves 1024->2048 (2/SIMD). R10 was
//    serial-chain bound (1 wave/SIMD, dur = 22 steps x ~5400 cyc); duration
//    scales with steps/wave, not wave count.
//  * Feats PREFETCH one step ahead: next step's 8 global loads issue before
//    the current step's MFMA/LDS phase -> ~1000 cyc HBM wait overlaps compute
//    instead of sitting on the chain. Consumed values bit-identical.
//  * __launch_bounds__(64,2) for the 2-wave/SIMD target.

#define KTAGS 50
#define TLEN 1024
#define NBATCH 256
#define SCHUNK 8
#define HALO 6
#define NCH (TLEN / SCHUNK)   // 128
#define START_TAG 48
#define STOP_TAG 49
#define SLS 68                // LDS row stride (f32)

typedef __attribute__((ext_vector_type(4))) float f32x4;
typedef __attribute__((ext_vector_type(8))) __bf16 bf16x8;

struct U16B { unsigned a, b, c, d; };
struct F8 { float2 q0, q1, q2, q3, r0, r1, r2, r3; };

static __device__ __forceinline__ unsigned pkbf(float lo, float hi) {
  unsigned r;
  asm("v_cvt_pk_bf16_f32 %0, %1, %2" : "=v"(r) : "v"(lo), "v"(hi));
  return r;
}
static __device__ __forceinline__ bf16x8 frag4(unsigned w0, unsigned w1,
                                               unsigned w2, unsigned w3) {
  U16B t{w0, w1, w2, w3};
  return __builtin_bit_cast(bf16x8, t);
}
static __device__ __forceinline__ bf16x8 fragq(uint4 q) {
  return __builtin_bit_cast(bf16x8, q);
}
static __device__ __forceinline__ float bperm(int srclane, float v) {
  return __uint_as_float(
      (unsigned)__builtin_amdgcn_ds_bpermute(srclane << 2, (int)__float_as_uint(v)));
}
static __device__ __forceinline__ float rdlane(float v, int l) {
  return __uint_as_float((unsigned)__builtin_amdgcn_readlane((int)__float_as_uint(v), l));
}
static __device__ __forceinline__ float lo16(unsigned w) { return __uint_as_float(w << 16); }
static __device__ __forceinline__ float hi16(unsigned w) { return __uint_as_float(w & 0xffff0000u); }

__global__ __launch_bounds__(64, 2) void crf_chunk(
    const float* __restrict__ feats, const float* __restrict__ trans,
    const unsigned char* __restrict__ mask, int* __restrict__ lengths,
    float* __restrict__ rho, float* __restrict__ sigma,
    float* __restrict__ rfin) {
  const int c = blockIdx.x;            // chunk
  const int b0 = blockIdx.y * 16;      // batch group base
  const int l = threadIdx.x;
  const int g = l >> 4;                // 0..3
  const int bl = l & 15;               // batch-in-group
  const int i0 = 8 * g;                // per-lane k-base within a 32-slice

  // ---- mask layout discriminator on byte-rows 0..1 (R8-proven).
  const uint4* m4u = reinterpret_cast<const uint4*>(mask);
  int bad = 0;
  #pragma unroll
  for (int r = 0; r < 2; ++r) {
    uint4 q = m4u[r * 64 + l];
    unsigned w[4] = {q.x, q.y, q.z, q.w};
    unsigned prevlast = 0xffu;
    #pragma unroll
    for (int k = 0; k < 4; ++k) {
      unsigned x = w[k];
      bad |= !(x == 0x01010101u || x == 0x00010101u || x == 0x00000101u ||
               x == 0x00000001u || x == 0u);
      if (k) bad |= (int)((prevlast == 0u) & ((x & 0xffu) != 0u));
      prevlast = x >> 24;
    }
    unsigned firstb = w[0] & 0xffu;
    unsigned pl = (unsigned)__shfl_up((int)prevlast, 1);
    bad |= (l == 0) ? (int)(firstb == 0u) : (int)((pl == 0u) & (firstb != 0u));
  }
  const bool is4byte = __any(bad);

  // ---- lengths: lane reads quarter g of mask row (b0+bl).
  int cnt = 0;
  if (!is4byte) {
    const uint4* mr = reinterpret_cast<const uint4*>(mask + (size_t)(b0 + bl) * TLEN);
    #pragma unroll
    for (int k = 0; k < 16; ++k) {
      uint4 q = mr[g * 16 + k];
      cnt += __popc(q.x) + __popc(q.y) + __popc(q.z) + __popc(q.w);
    }
  } else {
    const int4* mr = reinterpret_cast<const int4*>((const int*)mask + (size_t)(b0 + bl) * TLEN);
    for (int k = 0; k < 64; ++k) {
      int4 v = mr[g * 64 + k];
      cnt += (v.x != 0) + (v.y != 0) + (v.z != 0) + (v.w != 0);
    }
  }
  cnt += __shfl_xor(cnt, 16);
  cnt += __shfl_xor(cnt, 32);
  const int lenb = cnt;
  int ml = lenb;
  ml = max(ml, __shfl_xor(ml, 1));
  ml = max(ml, __shfl_xor(ml, 2));
  ml = max(ml, __shfl_xor(ml, 4));
  ml = max(ml, __shfl_xor(ml, 8));
  const int maxlen = ml;

  if (c == 0 && l < 16) lengths[b0 + l] = lenb;
  if (c != 0 && c * SCHUNK >= maxlen) return;

  __shared__ __align__(16) unsigned eLds[8 * 64 * 4];
  __shared__ __align__(16) float sl[16 * SLS];

  // ---- C-layout probe: C[m][n] = 1+m via delta_k0 outer product.
  bool csw;
  {
    unsigned pa = pkbf((g == 0) ? (1.f + (float)bl) : 0.f, 0.f);
    unsigned pb = pkbf((g == 0) ? 1.f : 0.f, 0.f);
    f32x4 z = {0.f, 0.f, 0.f, 0.f};
    f32x4 p = __builtin_amdgcn_mfma_f32_16x16x32_bf16(
        frag4(pa, 0u, 0u, 0u), frag4(pb, 0u, 0u, 0u), z, 0, 0, 0);
    csw = (rdlane(p[1], 17) < 4.f);
  }

  // ---- build E fragments: frag(s,nt) lane l elem(p,h): k=32s+8g+2p+h, n=16nt+bl.
  #pragma unroll
  for (int s = 0; s < 2; ++s) {
    #pragma unroll
    for (int nt = 0; nt < 4; ++nt) {
      const int n = 16 * nt + bl;
      unsigned w[4];
      #pragma unroll
      for (int p = 0; p < 4; ++p) {
        const int k0 = 32 * s + i0 + 2 * p;
        float v0 = 0.f, v1 = 0.f;
        if (n < KTAGS) {
          if (k0 < KTAGS)     v0 = __expf(trans[k0 * KTAGS + n]);
          if (k0 + 1 < KTAGS) v1 = __expf(trans[(k0 + 1) * KTAGS + n]);
        }
        w[p] = pkbf(v0, v1);
      }
      *reinterpret_cast<uint4*>(&eLds[((s * 4 + nt) * 64 + l) * 4]) =
          make_uint4(w[0], w[1], w[2], w[3]);
    }
  }

  // clamped y-half pair offsets (true k = 32+i0+2p+h; pads multiply zero E rows)
  const int yo0 = (32 + i0 + 0 <= 48) ? (32 + i0 + 0) : 42;
  const int yo1 = (32 + i0 + 2 <= 48) ? (32 + i0 + 2) : 42;
  const int yo2 = (32 + i0 + 4 <= 48) ? (32 + i0 + 4) : 42;
  const int yo3 = (32 + i0 + 6 <= 48) ? (32 + i0 + 6) : 42;

  const float* fbase = feats + (size_t)(b0 + bl) * TLEN * KTAGS;
  auto ldf = [&](int t) -> F8 {
    const float* fr = fbase + (size_t)t * KTAGS;
    F8 f;
    f.q0 = *(const float2*)(fr + i0);
    f.q1 = *(const float2*)(fr + i0 + 2);
    f.q2 = *(const float2*)(fr + i0 + 4);
    f.q3 = *(const float2*)(fr + i0 + 6);
    f.r0 = *(const float2*)(fr + yo0);
    f.r1 = *(const float2*)(fr + yo1);
    f.r2 = *(const float2*)(fr + yo2);
    f.r3 = *(const float2*)(fr + yo3);
    return f;
  };

  // ---- state init
  float lacc;
  unsigned aw0, aw1, aw2, aw3, aw4, aw5, aw6, aw7;
  {
    const int ti = (c == 0) ? 0 : (c * SCHUNK - 1 - HALO);
    F8 f = ldf(ti);
    float x0 = f.q0.x, x1 = f.q0.y, x2 = f.q1.x, x3 = f.q1.y;
    float x4 = f.q2.x, x5 = f.q2.y, x6 = f.q3.x, x7 = f.q3.y;
    float y0 = f.r0.x, y1 = f.r0.y, y2 = f.r1.x, y3 = f.r1.y;
    float y4 = f.r2.x, y5 = f.r2.y, y6 = f.r3.x, y7 = f.r3.y;
    if (c == 0) {   // exact init: alpha0 = f0 + trans[START][:]
      const float* tr = trans + START_TAG * KTAGS;
      x0 += tr[i0];     x1 += tr[i0 + 1]; x2 += tr[i0 + 2]; x3 += tr[i0 + 3];
      x4 += tr[i0 + 4]; x5 += tr[i0 + 5]; x6 += tr[i0 + 6]; x7 += tr[i0 + 7];
      y0 += tr[yo0]; y1 += tr[yo0 + 1];
      y2 += tr[yo1]; y3 += tr[yo1 + 1];
      y4 += tr[yo2]; y5 += tr[yo2 + 1];
      y6 += tr[yo3]; y7 += tr[yo3 + 1];
    }
    const float xr = bperm(bl, x1);   // alpha[b][1] from lane bl (g==0)
    lacc = xr;
    aw0 = pkbf(__expf(x0 - xr), __expf(x1 - xr));
    aw1 = pkbf(__expf(x2 - xr), __expf(x3 - xr));
    aw2 = pkbf(__expf(x4 - xr), __expf(x5 - xr));
    aw3 = pkbf(__expf(x6 - xr), __expf(x7 - xr));
    aw4 = pkbf(__expf(y0 - xr), __expf(y1 - xr));
    aw5 = pkbf(__expf(y2 - xr), __expf(y3 - xr));
    aw6 = pkbf(__expf(y4 - xr), __expf(y5 - xr));
    aw7 = pkbf(__expf(y6 - xr), __expf(y7 - xr));
  }

  const uint4* eq = reinterpret_cast<const uint4*>(eLds);

  auto step = [&](int t, const F8& f) {
    bf16x8 A0 = frag4(aw0, aw1, aw2, aw3);
    bf16x8 A1 = frag4(aw4, aw5, aw6, aw7);
    f32x4 z = {0.f, 0.f, 0.f, 0.f};
    f32x4 c0 = __builtin_amdgcn_mfma_f32_16x16x32_bf16(A0, fragq(eq[0 * 64 + l]), z, 0, 0, 0);
    f32x4 c1 = __builtin_amdgcn_mfma_f32_16x16x32_bf16(A0, fragq(eq[1 * 64 + l]), z, 0, 0, 0);
    f32x4 c2 = __builtin_amdgcn_mfma_f32_16x16x32_bf16(A0, fragq(eq[2 * 64 + l]), z, 0, 0, 0);
    f32x4 c3 = __builtin_amdgcn_mfma_f32_16x16x32_bf16(A0, fragq(eq[3 * 64 + l]), z, 0, 0, 0);
    c0 = __builtin_amdgcn_mfma_f32_16x16x32_bf16(A1, fragq(eq[4 * 64 + l]), c0, 0, 0, 0);
    c1 = __builtin_amdgcn_mfma_f32_16x16x32_bf16(A1, fragq(eq[5 * 64 + l]), c1, 0, 0, 0);
    c2 = __builtin_amdgcn_mfma_f32_16x16x32_bf16(A1, fragq(eq[6 * 64 + l]), c2, 0, 0, 0);
    c3 = __builtin_amdgcn_mfma_f32_16x16x32_bf16(A1, fragq(eq[7 * 64 + l]), c3, 0, 0, 0);

    // C -> sl[b][j], orientation per probe
    const int wb = g * 4;
    if (!csw) {
      sl[(wb + 0) * SLS + bl]      = c0[0];
      sl[(wb + 1) * SLS + bl]      = c0[1];
      sl[(wb + 2) * SLS + bl]      = c0[2];
      sl[(wb + 3) * SLS + bl]      = c0[3];
      sl[(wb + 0) * SLS + bl + 16] = c1[0];
      sl[(wb + 1) * SLS + bl + 16] = c1[1];
      sl[(wb + 2) * SLS + bl + 16] = c1[2];
      sl[(wb + 3) * SLS + bl + 16] = c1[3];
      sl[(wb + 0) * SLS + bl + 32] = c2[0];
      sl[(wb + 1) * SLS + bl + 32] = c2[1];
      sl[(wb + 2) * SLS + bl + 32] = c2[2];
      sl[(wb + 3) * SLS + bl + 32] = c2[3];
      sl[(wb + 0) * SLS + bl + 48] = c3[0];
      sl[(wb + 1) * SLS + bl + 48] = c3[1];
      sl[(wb + 2) * SLS + bl + 48] = c3[2];
      sl[(wb + 3) * SLS + bl + 48] = c3[3];
    } else {
      float* sw = &sl[bl * SLS + wb];
      sw[0]      = c0[0]; sw[1]      = c0[1]; sw[2]      = c0[2]; sw[3]      = c0[3];
      sw[16 + 0] = c1[0]; sw[16 + 1] = c1[1]; sw[16 + 2] = c1[2]; sw[16 + 3] = c1[3];
      sw[32 + 0] = c2[0]; sw[32 + 1] = c2[1]; sw[32 + 2] = c2[2]; sw[32 + 3] = c2[3];
      sw[48 + 0] = c3[0]; sw[48 + 1] = c3[1]; sw[48 + 2] = c3[2]; sw[48 + 3] = c3[3];
    }

    const float* sr = &sl[bl * SLS + i0];
    f32x4 sa = *(const f32x4*)(sr);
    f32x4 sb = *(const f32x4*)(sr + 4);
    f32x4 sc = *(const f32x4*)(sr + 32);
    f32x4 sd = *(const f32x4*)(sr + 36);

    float e0 = __expf(f.q0.x), e1 = __expf(f.q0.y), e2 = __expf(f.q1.x), e3 = __expf(f.q1.y);
    float e4 = __expf(f.q2.x), e5 = __expf(f.q2.y), e6 = __expf(f.q3.x), e7 = __expf(f.q3.y);
    float h0 = __expf(f.r0.x), h1 = __expf(f.r0.y), h2 = __expf(f.r1.x), h3 = __expf(f.r1.y);
    float h4 = __expf(f.r2.x), h5 = __expf(f.r2.y), h6 = __expf(f.r3.x), h7 = __expf(f.r3.y);

    float nrm = bperm(bl, sa[1] * e1);   // s[b][1]*ef[b][1] from lane bl (g==0)
    nrm = fmaxf(nrm, 1e-35f);            // NaN shield
    float rinv = __builtin_amdgcn_rcpf(nrm);

    float a0 = sa[0]*e0*rinv, a1 = sa[1]*e1*rinv, a2 = sa[2]*e2*rinv, a3 = sa[3]*e3*rinv;
    float a4 = sb[0]*e4*rinv, a5 = sb[1]*e5*rinv, a6 = sb[2]*e6*rinv, a7 = sb[3]*e7*rinv;
    float u0 = sc[0]*h0*rinv, u1 = sc[1]*h1*rinv, u2 = sc[2]*h2*rinv, u3 = sc[3]*h3*rinv;
    float u4 = sd[0]*h4*rinv, u5 = sd[1]*h5*rinv, u6 = sd[2]*h6*rinv, u7 = sd[3]*h7*rinv;

    unsigned n0 = pkbf(a0, a1), n1 = pkbf(a2, a3), n2 = pkbf(a4, a5), n3 = pkbf(a6, a7);
    unsigned n4 = pkbf(u0, u1), n5 = pkbf(u2, u3), n6 = pkbf(u4, u5), n7 = pkbf(u6, u7);

    const bool frz = (t >= lenb);   // reference mask semantics
    aw0 = frz ? aw0 : n0;  aw1 = frz ? aw1 : n1;
    aw2 = frz ? aw2 : n2;  aw3 = frz ? aw3 : n3;
    aw4 = frz ? aw4 : n4;  aw5 = frz ? aw5 : n5;
    aw6 = frz ? aw6 : n6;  aw7 = frz ? aw7 : n7;
    lacc = frz ? lacc : (lacc + __logf(nrm));
  };

  const int tendw = min((c + 1) * SCHUNK, maxlen) - 1;
  if (c != 0) {
    int t = c * SCHUNK - HALO;
    F8 P = ldf(t);
    #pragma unroll
    for (int h = 0; h < HALO; ++h) {         // t+1 <= c*S-1 <= TLEN-1: in-bounds
      F8 N = ldf(t + 1);
      step(t, P);
      P = N; ++t;
    }
    if (l < 16) rho[(size_t)(b0 + l) * NCH + c] = lacc;
    for (; t <= tendw; ++t) {
      F8 N = ldf(min(t + 1, TLEN - 1));      // final prefetch clamped, unused
      step(t, P);
      P = N;
    }
  } else {
    int t = 1;
    F8 P = ldf(1);
    for (; t <= tendw; ++t) {
      F8 N = ldf(min(t + 1, TLEN - 1));
      step(t, P);
      P = N;
    }
  }
  if (l < 16) sigma[(size_t)(b0 + l) * NCH + c] = lacc;

  // ---- final-chunk STOP reduction
  {
    float tot = 0.f;
    tot += lo16(aw0) * __expf(trans[(i0 + 0) * KTAGS + STOP_TAG]);
    tot += hi16(aw0) * __expf(trans[(i0 + 1) * KTAGS + STOP_TAG]);
    tot += lo16(aw1) * __expf(trans[(i0 + 2) * KTAGS + STOP_TAG]);
    tot += hi16(aw1) * __expf(trans[(i0 + 3) * KTAGS + STOP_TAG]);
    tot += lo16(aw2) * __expf(trans[(i0 + 4) * KTAGS + STOP_TAG]);
    tot += hi16(aw2) * __expf(trans[(i0 + 5) * KTAGS + STOP_TAG]);
    tot += lo16(aw3) * __expf(trans[(i0 + 6) * KTAGS + STOP_TAG]);
    tot += hi16(aw3) * __expf(trans[(i0 + 7) * KTAGS + STOP_TAG]);
    #pragma unroll
    for (int e = 0; e < 8; ++e) {
      const int kk = 32 + i0 + e;
      const int kc = kk < KTAGS ? kk : 0;
      float wv = (kk < KTAGS) ? __expf(trans[kc * KTAGS + STOP_TAG]) : 0.f;
      unsigned w = (e < 2) ? aw4 : (e < 4) ? aw5 : (e < 6) ? aw6 : aw7;
      float av = (e & 1) ? hi16(w) : lo16(w);
      tot += av * wv;
    }
    tot += __shfl_xor(tot, 16);
    tot += __shfl_xor(tot, 32);
    tot = fmaxf(tot, 1e-35f);
    const bool fin = (lenb > c * SCHUNK) && (lenb <= (c + 1) * SCHUNK);
    if (l < 16 && fin) rfin[(size_t)(b0 + l) * NCH + c] = lacc + __logf(tot);
  }
}

// ---- combine: chain scalar offsets, pick final chunk's LSE, reduce over b.
__global__ __launch_bounds__(256) void crf_combine(const int* __restrict__ lengths,
                                                   const float* __restrict__ rho,
                                                   const float* __restrict__ sigma,
                                                   const float* __restrict__ rfin,
                                                   float* __restrict__ out) {
  const int b = threadIdx.x;
  const int len = lengths[b];
  const int nch = (len + SCHUNK - 1) / SCHUNK;
  float delta = 0.f;
  for (int c = 1; c < nch; ++c)
    delta += sigma[b * NCH + c - 1] - rho[b * NCH + c];
  float res = rfin[b * NCH + nch - 1] + delta;
  __shared__ float red[256];
  red[b] = res;
  __syncthreads();
  for (int s = 128; s > 0; s >>= 1) {
    if (b < s) red[b] += red[b + s];
    __syncthreads();
  }
  if (b == 0) out[0] = red[0];
}

extern "C" void kernel_launch(void* const* d_in, const int* in_sizes, int n_in,
                              void* d_out, int out_size, void* d_ws, size_t ws_size,
                              hipStream_t stream) {
  const float* feats = (const float*)d_in[0];
  const float* trans = (const float*)d_in[1];
  const unsigned char* mask = (const unsigned char*)d_in[2];
  float* out = (float*)d_out;

  int* lengths = (int*)d_ws;                 // 256 ints
  float* rho = (float*)(lengths + 256);      // B*NCH
  float* sigma = rho + NBATCH * NCH;         // B*NCH
  float* rfin = sigma + NBATCH * NCH;        // B*NCH

  dim3 grid(NCH, NBATCH / 16);
  crf_chunk<<<grid, 64, 0, stream>>>(feats, trans, mask, lengths, rho, sigma, rfin);
  crf_combine<<<1, 256, 0, stream>>>(lengths, rho, sigma, rfin, out);
}

// Round 14
// 74.322 us; speedup vs baseline: 1.0061x; 1.0061x over previous
//
#include <hip/hip_runtime.h>

// CRF forward partition via ergodic chunked scan — MFMA formulation.
// B=256, T=1024, K=50. Wave = 16 batches x one chunk (S=8 steps + H=6 halo).
// Per step, 8x mfma_f32_16x16x32_bf16 compute S = X·E for 16 batches.
//
// R14 = R10's source VERBATIM (loads inside step, no prefetch loops — the
// R11/R13 prefetch restructure produced an unexplained NaN at S=16 and is
// abandoned) with one knob: SCHUNK 16->8. Single-variable test of the
// steps-per-wave lever: per-step chain ~5400 cyc looks wave-private
// (8 serialized feats loads x ~650 cyc); if so dur scales with steps/wave
// (22->14) and 2 waves/SIMD overlap the rest. S=8 chaining validated by R11.

#define KTAGS 50
#define TLEN 1024
#define NBATCH 256
#define SCHUNK 8
#define HALO 6
#define NCH (TLEN / SCHUNK)   // 128
#define START_TAG 48
#define STOP_TAG 49
#define SLS 68                // LDS row stride (f32)

typedef __attribute__((ext_vector_type(4))) float f32x4;
typedef __attribute__((ext_vector_type(8))) __bf16 bf16x8;

struct U16B { unsigned a, b, c, d; };

static __device__ __forceinline__ unsigned pkbf(float lo, float hi) {
  unsigned r;
  asm("v_cvt_pk_bf16_f32 %0, %1, %2" : "=v"(r) : "v"(lo), "v"(hi));
  return r;
}
static __device__ __forceinline__ bf16x8 frag4(unsigned w0, unsigned w1,
                                               unsigned w2, unsigned w3) {
  U16B t{w0, w1, w2, w3};
  return __builtin_bit_cast(bf16x8, t);
}
static __device__ __forceinline__ bf16x8 fragq(uint4 q) {
  return __builtin_bit_cast(bf16x8, q);
}
static __device__ __forceinline__ float bperm(int srclane, float v) {
  return __uint_as_float(
      (unsigned)__builtin_amdgcn_ds_bpermute(srclane << 2, (int)__float_as_uint(v)));
}
static __device__ __forceinline__ float rdlane(float v, int l) {
  return __uint_as_float((unsigned)__builtin_amdgcn_readlane((int)__float_as_uint(v), l));
}
static __device__ __forceinline__ float lo16(unsigned w) { return __uint_as_float(w << 16); }
static __device__ __forceinline__ float hi16(unsigned w) { return __uint_as_float(w & 0xffff0000u); }

__global__ __launch_bounds__(64, 1) void crf_chunk(
    const float* __restrict__ feats, const float* __restrict__ trans,
    const unsigned char* __restrict__ mask, int* __restrict__ lengths,
    float* __restrict__ rho, float* __restrict__ sigma,
    float* __restrict__ rfin) {
  const int c = blockIdx.x;            // chunk
  const int b0 = blockIdx.y * 16;      // batch group base
  const int l = threadIdx.x;
  const int g = l >> 4;                // 0..3
  const int bl = l & 15;               // batch-in-group
  const int i0 = 8 * g;                // per-lane k-base within a 32-slice

  // ---- mask layout discriminator on byte-rows 0..1 (R8-proven).
  const uint4* m4u = reinterpret_cast<const uint4*>(mask);
  int bad = 0;
  #pragma unroll
  for (int r = 0; r < 2; ++r) {
    uint4 q = m4u[r * 64 + l];
    unsigned w[4] = {q.x, q.y, q.z, q.w};
    unsigned prevlast = 0xffu;
    #pragma unroll
    for (int k = 0; k < 4; ++k) {
      unsigned x = w[k];
      bad |= !(x == 0x01010101u || x == 0x00010101u || x == 0x00000101u ||
               x == 0x00000001u || x == 0u);
      if (k) bad |= (int)((prevlast == 0u) & ((x & 0xffu) != 0u));
      prevlast = x >> 24;
    }
    unsigned firstb = w[0] & 0xffu;
    unsigned pl = (unsigned)__shfl_up((int)prevlast, 1);
    bad |= (l == 0) ? (int)(firstb == 0u) : (int)((pl == 0u) & (firstb != 0u));
  }
  const bool is4byte = __any(bad);

  // ---- lengths: lane reads quarter g of mask row (b0+bl).
  int cnt = 0;
  if (!is4byte) {
    const uint4* mr = reinterpret_cast<const uint4*>(mask + (size_t)(b0 + bl) * TLEN);
    #pragma unroll
    for (int k = 0; k < 16; ++k) {
      uint4 q = mr[g * 16 + k];
      cnt += __popc(q.x) + __popc(q.y) + __popc(q.z) + __popc(q.w);
    }
  } else {
    const int4* mr = reinterpret_cast<const int4*>((const int*)mask + (size_t)(b0 + bl) * TLEN);
    for (int k = 0; k < 64; ++k) {
      int4 v = mr[g * 64 + k];
      cnt += (v.x != 0) + (v.y != 0) + (v.z != 0) + (v.w != 0);
    }
  }
  cnt += __shfl_xor(cnt, 16);
  cnt += __shfl_xor(cnt, 32);
  const int lenb = cnt;
  int ml = lenb;
  ml = max(ml, __shfl_xor(ml, 1));
  ml = max(ml, __shfl_xor(ml, 2));
  ml = max(ml, __shfl_xor(ml, 4));
  ml = max(ml, __shfl_xor(ml, 8));
  const int maxlen = ml;

  if (c == 0 && l < 16) lengths[b0 + l] = lenb;
  if (c != 0 && c * SCHUNK >= maxlen) return;

  __shared__ __align__(16) unsigned eLds[8 * 64 * 4];
  __shared__ __align__(16) float sl[16 * SLS];

  // ---- C-layout probe: C[m][n] = 1+m via delta_k0 outer product.
  bool csw;
  {
    unsigned pa = pkbf((g == 0) ? (1.f + (float)bl) : 0.f, 0.f);
    unsigned pb = pkbf((g == 0) ? 1.f : 0.f, 0.f);
    f32x4 z = {0.f, 0.f, 0.f, 0.f};
    f32x4 p = __builtin_amdgcn_mfma_f32_16x16x32_bf16(
        frag4(pa, 0u, 0u, 0u), frag4(pb, 0u, 0u, 0u), z, 0, 0, 0);
    // m89: p[r]=C[4g+r][bl] -> lane17 reg1 = 6 ; swapped -> 2
    csw = (rdlane(p[1], 17) < 4.f);
  }

  // ---- build E fragments: frag(s,nt) lane l elem(p,h): k=32s+8g+2p+h, n=16nt+bl.
  #pragma unroll
  for (int s = 0; s < 2; ++s) {
    #pragma unroll
    for (int nt = 0; nt < 4; ++nt) {
      const int n = 16 * nt + bl;
      unsigned w[4];
      #pragma unroll
      for (int p = 0; p < 4; ++p) {
        const int k0 = 32 * s + i0 + 2 * p;
        float v0 = 0.f, v1 = 0.f;
        if (n < KTAGS) {
          if (k0 < KTAGS)     v0 = __expf(trans[k0 * KTAGS + n]);
          if (k0 + 1 < KTAGS) v1 = __expf(trans[(k0 + 1) * KTAGS + n]);
        }
        w[p] = pkbf(v0, v1);
      }
      *reinterpret_cast<uint4*>(&eLds[((s * 4 + nt) * 64 + l) * 4]) =
          make_uint4(w[0], w[1], w[2], w[3]);
    }
  }

  // clamped y-half pair offsets (true k = 32+i0+2p+h; pads multiply zero E rows)
  const int yo0 = (32 + i0 + 0 <= 48) ? (32 + i0 + 0) : 42;
  const int yo1 = (32 + i0 + 2 <= 48) ? (32 + i0 + 2) : 42;
  const int yo2 = (32 + i0 + 4 <= 48) ? (32 + i0 + 4) : 42;
  const int yo3 = (32 + i0 + 6 <= 48) ? (32 + i0 + 6) : 42;

  // ---- state init
  float lacc;
  unsigned aw0, aw1, aw2, aw3, aw4, aw5, aw6, aw7;
  {
    const int ti = (c == 0) ? 0 : (c * SCHUNK - 1 - HALO);
    const float* fr = feats + ((size_t)(b0 + bl) * TLEN + ti) * KTAGS;
    float2 q0 = *(const float2*)(fr + i0);
    float2 q1 = *(const float2*)(fr + i0 + 2);
    float2 q2 = *(const float2*)(fr + i0 + 4);
    float2 q3 = *(const float2*)(fr + i0 + 6);
    float2 r0 = *(const float2*)(fr + yo0);
    float2 r1 = *(const float2*)(fr + yo1);
    float2 r2 = *(const float2*)(fr + yo2);
    float2 r3 = *(const float2*)(fr + yo3);
    float x0 = q0.x, x1 = q0.y, x2 = q1.x, x3 = q1.y;
    float x4 = q2.x, x5 = q2.y, x6 = q3.x, x7 = q3.y;
    float y0 = r0.x, y1 = r0.y, y2 = r1.x, y3 = r1.y;
    float y4 = r2.x, y5 = r2.y, y6 = r3.x, y7 = r3.y;
    if (c == 0) {   // exact init: alpha0 = f0 + trans[START][:]
      const float* tr = trans + START_TAG * KTAGS;
      x0 += tr[i0];     x1 += tr[i0 + 1]; x2 += tr[i0 + 2]; x3 += tr[i0 + 3];
      x4 += tr[i0 + 4]; x5 += tr[i0 + 5]; x6 += tr[i0 + 6]; x7 += tr[i0 + 7];
      y0 += tr[yo0]; y1 += tr[yo0 + 1];
      y2 += tr[yo1]; y3 += tr[yo1 + 1];
      y4 += tr[yo2]; y5 += tr[yo2 + 1];
      y6 += tr[yo3]; y7 += tr[yo3 + 1];
    }
    const float xr = bperm(bl, x1);   // alpha[b][1] from lane bl (g==0)
    lacc = xr;
    aw0 = pkbf(__expf(x0 - xr), __expf(x1 - xr));
    aw1 = pkbf(__expf(x2 - xr), __expf(x3 - xr));
    aw2 = pkbf(__expf(x4 - xr), __expf(x5 - xr));
    aw3 = pkbf(__expf(x6 - xr), __expf(x7 - xr));
    aw4 = pkbf(__expf(y0 - xr), __expf(y1 - xr));
    aw5 = pkbf(__expf(y2 - xr), __expf(y3 - xr));
    aw6 = pkbf(__expf(y4 - xr), __expf(y5 - xr));
    aw7 = pkbf(__expf(y6 - xr), __expf(y7 - xr));
  }

  const uint4* eq = reinterpret_cast<const uint4*>(eLds);

  auto step = [&](int t) {
    // feats for ef(t) — issued at step top, consumed after MFMA+LDS phase
    const float* fr = feats + ((size_t)(b0 + bl) * TLEN + t) * KTAGS;
    float2 q0 = *(const float2*)(fr + i0);
    float2 q1 = *(const float2*)(fr + i0 + 2);
    float2 q2 = *(const float2*)(fr + i0 + 4);
    float2 q3 = *(const float2*)(fr + i0 + 6);
    float2 r0 = *(const float2*)(fr + yo0);
    float2 r1 = *(const float2*)(fr + yo1);
    float2 r2 = *(const float2*)(fr + yo2);
    float2 r3 = *(const float2*)(fr + yo3);

    bf16x8 A0 = frag4(aw0, aw1, aw2, aw3);
    bf16x8 A1 = frag4(aw4, aw5, aw6, aw7);
    f32x4 z = {0.f, 0.f, 0.f, 0.f};
    f32x4 c0 = __builtin_amdgcn_mfma_f32_16x16x32_bf16(A0, fragq(eq[0 * 64 + l]), z, 0, 0, 0);
    f32x4 c1 = __builtin_amdgcn_mfma_f32_16x16x32_bf16(A0, fragq(eq[1 * 64 + l]), z, 0, 0, 0);
    f32x4 c2 = __builtin_amdgcn_mfma_f32_16x16x32_bf16(A0, fragq(eq[2 * 64 + l]), z, 0, 0, 0);
    f32x4 c3 = __builtin_amdgcn_mfma_f32_16x16x32_bf16(A0, fragq(eq[3 * 64 + l]), z, 0, 0, 0);
    c0 = __builtin_amdgcn_mfma_f32_16x16x32_bf16(A1, fragq(eq[4 * 64 + l]), c0, 0, 0, 0);
    c1 = __builtin_amdgcn_mfma_f32_16x16x32_bf16(A1, fragq(eq[5 * 64 + l]), c1, 0, 0, 0);
    c2 = __builtin_amdgcn_mfma_f32_16x16x32_bf16(A1, fragq(eq[6 * 64 + l]), c2, 0, 0, 0);
    c3 = __builtin_amdgcn_mfma_f32_16x16x32_bf16(A1, fragq(eq[7 * 64 + l]), c3, 0, 0, 0);

    // C -> sl[b][j], orientation per probe
    const int wb = g * 4;
    if (!csw) {
      sl[(wb + 0) * SLS + bl]      = c0[0];
      sl[(wb + 1) * SLS + bl]      = c0[1];
      sl[(wb + 2) * SLS + bl]      = c0[2];
      sl[(wb + 3) * SLS + bl]      = c0[3];
      sl[(wb + 0) * SLS + bl + 16] = c1[0];
      sl[(wb + 1) * SLS + bl + 16] = c1[1];
      sl[(wb + 2) * SLS + bl + 16] = c1[2];
      sl[(wb + 3) * SLS + bl + 16] = c1[3];
      sl[(wb + 0) * SLS + bl + 32] = c2[0];
      sl[(wb + 1) * SLS + bl + 32] = c2[1];
      sl[(wb + 2) * SLS + bl + 32] = c2[2];
      sl[(wb + 3) * SLS + bl + 32] = c2[3];
      sl[(wb + 0) * SLS + bl + 48] = c3[0];
      sl[(wb + 1) * SLS + bl + 48] = c3[1];
      sl[(wb + 2) * SLS + bl + 48] = c3[2];
      sl[(wb + 3) * SLS + bl + 48] = c3[3];
    } else {
      float* sw = &sl[bl * SLS + wb];
      sw[0]      = c0[0]; sw[1]      = c0[1]; sw[2]      = c0[2]; sw[3]      = c0[3];
      sw[16 + 0] = c1[0]; sw[16 + 1] = c1[1]; sw[16 + 2] = c1[2]; sw[16 + 3] = c1[3];
      sw[32 + 0] = c2[0]; sw[32 + 1] = c2[1]; sw[32 + 2] = c2[2]; sw[32 + 3] = c2[3];
      sw[48 + 0] = c3[0]; sw[48 + 1] = c3[1]; sw[48 + 2] = c3[2]; sw[48 + 3] = c3[3];
    }

    const float* sr = &sl[bl * SLS + i0];
    f32x4 sa = *(const f32x4*)(sr);
    f32x4 sb = *(const f32x4*)(sr + 4);
    f32x4 sc = *(const f32x4*)(sr + 32);
    f32x4 sd = *(const f32x4*)(sr + 36);

    float e0 = __expf(q0.x), e1 = __expf(q0.y), e2 = __expf(q1.x), e3 = __expf(q1.y);
    float e4 = __expf(q2.x), e5 = __expf(q2.y), e6 = __expf(q3.x), e7 = __expf(q3.y);
    float h0 = __expf(r0.x), h1 = __expf(r0.y), h2 = __expf(r1.x), h3 = __expf(r1.y);
    float h4 = __expf(r2.x), h5 = __expf(r2.y), h6 = __expf(r3.x), h7 = __expf(r3.y);

    float nrm = bperm(bl, sa[1] * e1);   // s[b][1]*ef[b][1] from lane bl (g==0)
    nrm = fmaxf(nrm, 1e-35f);            // NaN shield
    float rinv = __builtin_amdgcn_rcpf(nrm);

    float a0 = sa[0]*e0*rinv, a1 = sa[1]*e1*rinv, a2 = sa[2]*e2*rinv, a3 = sa[3]*e3*rinv;
    float a4 = sb[0]*e4*rinv, a5 = sb[1]*e5*rinv, a6 = sb[2]*e6*rinv, a7 = sb[3]*e7*rinv;
    float u0 = sc[0]*h0*rinv, u1 = sc[1]*h1*rinv, u2 = sc[2]*h2*rinv, u3 = sc[3]*h3*rinv;
    float u4 = sd[0]*h4*rinv, u5 = sd[1]*h5*rinv, u6 = sd[2]*h6*rinv, u7 = sd[3]*h7*rinv;

    unsigned n0 = pkbf(a0, a1), n1 = pkbf(a2, a3), n2 = pkbf(a4, a5), n3 = pkbf(a6, a7);
    unsigned n4 = pkbf(u0, u1), n5 = pkbf(u2, u3), n6 = pkbf(u4, u5), n7 = pkbf(u6, u7);

    const bool frz = (t >= lenb);   // reference mask semantics
    aw0 = frz ? aw0 : n0;  aw1 = frz ? aw1 : n1;
    aw2 = frz ? aw2 : n2;  aw3 = frz ? aw3 : n3;
    aw4 = frz ? aw4 : n4;  aw5 = frz ? aw5 : n5;
    aw6 = frz ? aw6 : n6;  aw7 = frz ? aw7 : n7;
    lacc = frz ? lacc : (lacc + __logf(nrm));
  };

  const int tendw = min((c + 1) * SCHUNK, maxlen) - 1;
  if (c != 0) {
    const int tb = c * SCHUNK - HALO;
    #pragma unroll
    for (int h = 0; h < HALO; ++h) step(tb + h);
    if (l < 16) rho[(size_t)(b0 + l) * NCH + c] = lacc;
    for (int t = c * SCHUNK; t <= tendw; ++t) step(t);
  } else {
    for (int t = 1; t <= tendw; ++t) step(t);
  }
  if (l < 16) sigma[(size_t)(b0 + l) * NCH + c] = lacc;

  // ---- final-chunk STOP reduction
  {
    float tot = 0.f;
    tot += lo16(aw0) * __expf(trans[(i0 + 0) * KTAGS + STOP_TAG]);
    tot += hi16(aw0) * __expf(trans[(i0 + 1) * KTAGS + STOP_TAG]);
    tot += lo16(aw1) * __expf(trans[(i0 + 2) * KTAGS + STOP_TAG]);
    tot += hi16(aw1) * __expf(trans[(i0 + 3) * KTAGS + STOP_TAG]);
    tot += lo16(aw2) * __expf(trans[(i0 + 4) * KTAGS + STOP_TAG]);
    tot += hi16(aw2) * __expf(trans[(i0 + 5) * KTAGS + STOP_TAG]);
    tot += lo16(aw3) * __expf(trans[(i0 + 6) * KTAGS + STOP_TAG]);
    tot += hi16(aw3) * __expf(trans[(i0 + 7) * KTAGS + STOP_TAG]);
    #pragma unroll
    for (int e = 0; e < 8; ++e) {
      const int kk = 32 + i0 + e;
      const int kc = kk < KTAGS ? kk : 0;
      float wv = (kk < KTAGS) ? __expf(trans[kc * KTAGS + STOP_TAG]) : 0.f;
      unsigned w = (e < 2) ? aw4 : (e < 4) ? aw5 : (e < 6) ? aw6 : aw7;
      float av = (e & 1) ? hi16(w) : lo16(w);
      tot += av * wv;
    }
    tot += __shfl_xor(tot, 16);
    tot += __shfl_xor(tot, 32);
    tot = fmaxf(tot, 1e-35f);
    const bool fin = (lenb > c * SCHUNK) && (lenb <= (c + 1) * SCHUNK);
    if (l < 16 && fin) rfin[(size_t)(b0 + l) * NCH + c] = lacc + __logf(tot);
  }
}

// ---- combine: chain scalar offsets, pick final chunk's LSE, reduce over b.
__global__ __launch_bounds__(256) void crf_combine(const int* __restrict__ lengths,
                                                   const float* __restrict__ rho,
                                                   const float* __restrict__ sigma,
                                                   const float* __restrict__ rfin,
                                                   float* __restrict__ out) {
  const int b = threadIdx.x;
  const int len = lengths[b];
  const int nch = (len + SCHUNK - 1) / SCHUNK;
  float delta = 0.f;
  for (int c = 1; c < nch; ++c)
    delta += sigma[b * NCH + c - 1] - rho[b * NCH + c];
  float res = rfin[b * NCH + nch - 1] + delta;
  __shared__ float red[256];
  red[b] = res;
  __syncthreads();
  for (int s = 128; s > 0; s >>= 1) {
    if (b < s) red[b] += red[b + s];
    __syncthreads();
  }
  if (b == 0) out[0] = red[0];
}

extern "C" void kernel_launch(void* const* d_in, const int* in_sizes, int n_in,
                              void* d_out, int out_size, void* d_ws, size_t ws_size,
                              hipStream_t stream) {
  const float* feats = (const float*)d_in[0];
  const float* trans = (const float*)d_in[1];
  const unsigned char* mask = (const unsigned char*)d_in[2];
  float* out = (float*)d_out;

  int* lengths = (int*)d_ws;                 // 256 ints
  float* rho = (float*)(lengths + 256);      // B*NCH
  float* sigma = rho + NBATCH * NCH;         // B*NCH
  float* rfin = sigma + NBATCH * NCH;        // B*NCH

  dim3 grid(NCH, NBATCH / 16);
  crf_chunk<<<grid, 64, 0, stream>>>(feats, trans, mask, lengths, rho, sigma, rfin);
  crf_combine<<<1, 256, 0, stream>>>(lengths, rho, sigma, rfin, out);
}

// Round 15
// 60.978 us; speedup vs baseline: 1.2263x; 1.2188x over previous
//
#include <hip/hip_runtime.h>

// CRF forward partition via ergodic chunked scan — MFMA formulation.
// B=256, T=1024, K=50. Wave = 16 batches x TWO chunks (cA=bx, cB=bx+32),
// S=16 steps + H=6 halo each, phase-interleaved for intra-wave ILP.
//
// R15 = R10's data path VERBATIM per task, two tasks per wave:
//   phases: {loadA,loadB} -> {8 MFMA A, 8 MFMA B} -> {postA} -> {postB}.
// B's MFMAs/loads overlap A's LDS+VALU chain (R10 idles 87% of VALU slots at
// 1 wave/SIMD; prefetch-d1 was neutral (R11 vs R14) so the stall is
// chain-internal, not load-wait). Separate sl buffers per task. Wave count
// 512. Tails handle unequal trip counts; chaining/combine unchanged.

#define KTAGS 50
#define TLEN 1024
#define NBATCH 256
#define SCHUNK 16
#define HALO 6
#define NCH (TLEN / SCHUNK)   // 64
#define START_TAG 48
#define STOP_TAG 49
#define SLS 68                // LDS row stride (f32)

typedef __attribute__((ext_vector_type(4))) float f32x4;
typedef __attribute__((ext_vector_type(8))) __bf16 bf16x8;

struct U16B { unsigned a, b, c, d; };

static __device__ __forceinline__ unsigned pkbf(float lo, float hi) {
  unsigned r;
  asm("v_cvt_pk_bf16_f32 %0, %1, %2" : "=v"(r) : "v"(lo), "v"(hi));
  return r;
}
static __device__ __forceinline__ bf16x8 frag4(unsigned w0, unsigned w1,
                                               unsigned w2, unsigned w3) {
  U16B t{w0, w1, w2, w3};
  return __builtin_bit_cast(bf16x8, t);
}
static __device__ __forceinline__ bf16x8 fragq(uint4 q) {
  return __builtin_bit_cast(bf16x8, q);
}
static __device__ __forceinline__ float bperm(int srclane, float v) {
  return __uint_as_float(
      (unsigned)__builtin_amdgcn_ds_bpermute(srclane << 2, (int)__float_as_uint(v)));
}
static __device__ __forceinline__ float rdlane(float v, int l) {
  return __uint_as_float((unsigned)__builtin_amdgcn_readlane((int)__float_as_uint(v), l));
}
static __device__ __forceinline__ float lo16(unsigned w) { return __uint_as_float(w << 16); }
static __device__ __forceinline__ float hi16(unsigned w) { return __uint_as_float(w & 0xffff0000u); }

// ---- per-task step phases (S = A or B), R10's step body verbatim ----------
#define STEP_LOAD(S, t)                                                       \
  const float* fr_##S = feats + ((size_t)(b0 + bl) * TLEN + (size_t)(t)) * KTAGS; \
  float2 q0_##S = *(const float2*)(fr_##S + i0);                              \
  float2 q1_##S = *(const float2*)(fr_##S + i0 + 2);                          \
  float2 q2_##S = *(const float2*)(fr_##S + i0 + 4);                          \
  float2 q3_##S = *(const float2*)(fr_##S + i0 + 6);                          \
  float2 r0_##S = *(const float2*)(fr_##S + yo0);                             \
  float2 r1_##S = *(const float2*)(fr_##S + yo1);                             \
  float2 r2_##S = *(const float2*)(fr_##S + yo2);                             \
  float2 r3_##S = *(const float2*)(fr_##S + yo3);

#define STEP_MFMA(S)                                                          \
  bf16x8 A0_##S = frag4(aw##S##0, aw##S##1, aw##S##2, aw##S##3);              \
  bf16x8 A1_##S = frag4(aw##S##4, aw##S##5, aw##S##6, aw##S##7);              \
  f32x4 z_##S = {0.f, 0.f, 0.f, 0.f};                                         \
  f32x4 c0_##S = __builtin_amdgcn_mfma_f32_16x16x32_bf16(A0_##S, fragq(eq[0 * 64 + l]), z_##S, 0, 0, 0); \
  f32x4 c1_##S = __builtin_amdgcn_mfma_f32_16x16x32_bf16(A0_##S, fragq(eq[1 * 64 + l]), z_##S, 0, 0, 0); \
  f32x4 c2_##S = __builtin_amdgcn_mfma_f32_16x16x32_bf16(A0_##S, fragq(eq[2 * 64 + l]), z_##S, 0, 0, 0); \
  f32x4 c3_##S = __builtin_amdgcn_mfma_f32_16x16x32_bf16(A0_##S, fragq(eq[3 * 64 + l]), z_##S, 0, 0, 0); \
  c0_##S = __builtin_amdgcn_mfma_f32_16x16x32_bf16(A1_##S, fragq(eq[4 * 64 + l]), c0_##S, 0, 0, 0); \
  c1_##S = __builtin_amdgcn_mfma_f32_16x16x32_bf16(A1_##S, fragq(eq[5 * 64 + l]), c1_##S, 0, 0, 0); \
  c2_##S = __builtin_amdgcn_mfma_f32_16x16x32_bf16(A1_##S, fragq(eq[6 * 64 + l]), c2_##S, 0, 0, 0); \
  c3_##S = __builtin_amdgcn_mfma_f32_16x16x32_bf16(A1_##S, fragq(eq[7 * 64 + l]), c3_##S, 0, 0, 0);

#define STEP_POST(S, t)                                                       \
  {                                                                           \
    const int wb = g * 4;                                                     \
    if (!csw) {                                                               \
      sl##S[(wb + 0) * SLS + bl]      = c0_##S[0];                            \
      sl##S[(wb + 1) * SLS + bl]      = c0_##S[1];                            \
      sl##S[(wb + 2) * SLS + bl]      = c0_##S[2];                            \
      sl##S[(wb + 3) * SLS + bl]      = c0_##S[3];                            \
      sl##S[(wb + 0) * SLS + bl + 16] = c1_##S[0];                            \
      sl##S[(wb + 1) * SLS + bl + 16] = c1_##S[1];                            \
      sl##S[(wb + 2) * SLS + bl + 16] = c1_##S[2];                            \
      sl##S[(wb + 3) * SLS + bl + 16] = c1_##S[3];                            \
      sl##S[(wb + 0) * SLS + bl + 32] = c2_##S[0];                            \
      sl##S[(wb + 1) * SLS + bl + 32] = c2_##S[1];                            \
      sl##S[(wb + 2) * SLS + bl + 32] = c2_##S[2];                            \
      sl##S[(wb + 3) * SLS + bl + 32] = c2_##S[3];                            \
      sl##S[(wb + 0) * SLS + bl + 48] = c3_##S[0];                            \
      sl##S[(wb + 1) * SLS + bl + 48] = c3_##S[1];                            \
      sl##S[(wb + 2) * SLS + bl + 48] = c3_##S[2];                            \
      sl##S[(wb + 3) * SLS + bl + 48] = c3_##S[3];                            \
    } else {                                                                  \
      float* sw = &sl##S[bl * SLS + wb];                                      \
      sw[0]      = c0_##S[0]; sw[1]      = c0_##S[1];                         \
      sw[2]      = c0_##S[2]; sw[3]      = c0_##S[3];                         \
      sw[16 + 0] = c1_##S[0]; sw[16 + 1] = c1_##S[1];                         \
      sw[16 + 2] = c1_##S[2]; sw[16 + 3] = c1_##S[3];                         \
      sw[32 + 0] = c2_##S[0]; sw[32 + 1] = c2_##S[1];                         \
      sw[32 + 2] = c2_##S[2]; sw[32 + 3] = c2_##S[3];                         \
      sw[48 + 0] = c3_##S[0]; sw[48 + 1] = c3_##S[1];                         \
      sw[48 + 2] = c3_##S[2]; sw[48 + 3] = c3_##S[3];                         \
    }                                                                         \
    const float* sr = &sl##S[bl * SLS + i0];                                  \
    f32x4 sa = *(const f32x4*)(sr);                                           \
    f32x4 sb = *(const f32x4*)(sr + 4);                                       \
    f32x4 sc = *(const f32x4*)(sr + 32);                                      \
    f32x4 sd = *(const f32x4*)(sr + 36);                                      \
    float e0 = __expf(q0_##S.x), e1 = __expf(q0_##S.y);                       \
    float e2 = __expf(q1_##S.x), e3 = __expf(q1_##S.y);                       \
    float e4 = __expf(q2_##S.x), e5 = __expf(q2_##S.y);                       \
    float e6 = __expf(q3_##S.x), e7 = __expf(q3_##S.y);                       \
    float h0 = __expf(r0_##S.x), h1 = __expf(r0_##S.y);                       \
    float h2 = __expf(r1_##S.x), h3 = __expf(r1_##S.y);                       \
    float h4 = __expf(r2_##S.x), h5 = __expf(r2_##S.y);                       \
    float h6 = __expf(r3_##S.x), h7 = __expf(r3_##S.y);                       \
    float nrm = bperm(bl, sa[1] * e1);                                        \
    nrm = fmaxf(nrm, 1e-35f);                                                 \
    float rinv = __builtin_amdgcn_rcpf(nrm);                                  \
    float a0 = sa[0]*e0*rinv, a1 = sa[1]*e1*rinv;                             \
    float a2 = sa[2]*e2*rinv, a3 = sa[3]*e3*rinv;                             \
    float a4 = sb[0]*e4*rinv, a5 = sb[1]*e5*rinv;                             \
    float a6 = sb[2]*e6*rinv, a7 = sb[3]*e7*rinv;                             \
    float u0 = sc[0]*h0*rinv, u1 = sc[1]*h1*rinv;                             \
    float u2 = sc[2]*h2*rinv, u3 = sc[3]*h3*rinv;                             \
    float u4 = sd[0]*h4*rinv, u5 = sd[1]*h5*rinv;                             \
    float u6 = sd[2]*h6*rinv, u7 = sd[3]*h7*rinv;                             \
    unsigned n0 = pkbf(a0, a1), n1 = pkbf(a2, a3);                            \
    unsigned n2 = pkbf(a4, a5), n3 = pkbf(a6, a7);                            \
    unsigned n4 = pkbf(u0, u1), n5 = pkbf(u2, u3);                            \
    unsigned n6 = pkbf(u4, u5), n7 = pkbf(u6, u7);                            \
    const bool frz = ((t) >= lenb);                                           \
    aw##S##0 = frz ? aw##S##0 : n0;  aw##S##1 = frz ? aw##S##1 : n1;          \
    aw##S##2 = frz ? aw##S##2 : n2;  aw##S##3 = frz ? aw##S##3 : n3;          \
    aw##S##4 = frz ? aw##S##4 : n4;  aw##S##5 = frz ? aw##S##5 : n5;          \
    aw##S##6 = frz ? aw##S##6 : n6;  aw##S##7 = frz ? aw##S##7 : n7;          \
    lacc##S = frz ? lacc##S : (lacc##S + __logf(nrm));                        \
  }

#define INITSTATE(S, cX)                                                      \
  {                                                                           \
    const int ti = ((cX) == 0) ? 0 : ((cX) * SCHUNK - 1 - HALO);              \
    const float* fr = feats + ((size_t)(b0 + bl) * TLEN + ti) * KTAGS;        \
    float2 q0 = *(const float2*)(fr + i0);                                    \
    float2 q1 = *(const float2*)(fr + i0 + 2);                                \
    float2 q2 = *(const float2*)(fr + i0 + 4);                                \
    float2 q3 = *(const float2*)(fr + i0 + 6);                                \
    float2 r0 = *(const float2*)(fr + yo0);                                   \
    float2 r1 = *(const float2*)(fr + yo1);                                   \
    float2 r2 = *(const float2*)(fr + yo2);                                   \
    float2 r3 = *(const float2*)(fr + yo3);                                   \
    float x0 = q0.x, x1 = q0.y, x2 = q1.x, x3 = q1.y;                         \
    float x4 = q2.x, x5 = q2.y, x6 = q3.x, x7 = q3.y;                         \
    float y0 = r0.x, y1 = r0.y, y2 = r1.x, y3 = r1.y;                         \
    float y4 = r2.x, y5 = r2.y, y6 = r3.x, y7 = r3.y;                         \
    if ((cX) == 0) {                                                          \
      const float* tr = trans + START_TAG * KTAGS;                            \
      x0 += tr[i0];     x1 += tr[i0 + 1]; x2 += tr[i0 + 2]; x3 += tr[i0 + 3]; \
      x4 += tr[i0 + 4]; x5 += tr[i0 + 5]; x6 += tr[i0 + 6]; x7 += tr[i0 + 7]; \
      y0 += tr[yo0]; y1 += tr[yo0 + 1];                                       \
      y2 += tr[yo1]; y3 += tr[yo1 + 1];                                       \
      y4 += tr[yo2]; y5 += tr[yo2 + 1];                                       \
      y6 += tr[yo3]; y7 += tr[yo3 + 1];                                       \
    }                                                                         \
    const float xr = bperm(bl, x1);                                           \
    lacc##S = xr;                                                             \
    aw##S##0 = pkbf(__expf(x0 - xr), __expf(x1 - xr));                        \
    aw##S##1 = pkbf(__expf(x2 - xr), __expf(x3 - xr));                        \
    aw##S##2 = pkbf(__expf(x4 - xr), __expf(x5 - xr));                        \
    aw##S##3 = pkbf(__expf(x6 - xr), __expf(x7 - xr));                        \
    aw##S##4 = pkbf(__expf(y0 - xr), __expf(y1 - xr));                        \
    aw##S##5 = pkbf(__expf(y2 - xr), __expf(y3 - xr));                        \
    aw##S##6 = pkbf(__expf(y4 - xr), __expf(y5 - xr));                        \
    aw##S##7 = pkbf(__expf(y6 - xr), __expf(y7 - xr));                        \
  }

#define STOPRED(S, cX)                                                        \
  {                                                                           \
    float tot = 0.f;                                                          \
    tot += lo16(aw##S##0) * __expf(trans[(i0 + 0) * KTAGS + STOP_TAG]);       \
    tot += hi16(aw##S##0) * __expf(trans[(i0 + 1) * KTAGS + STOP_TAG]);       \
    tot += lo16(aw##S##1) * __expf(trans[(i0 + 2) * KTAGS + STOP_TAG]);       \
    tot += hi16(aw##S##1) * __expf(trans[(i0 + 3) * KTAGS + STOP_TAG]);       \
    tot += lo16(aw##S##2) * __expf(trans[(i0 + 4) * KTAGS + STOP_TAG]);       \
    tot += hi16(aw##S##2) * __expf(trans[(i0 + 5) * KTAGS + STOP_TAG]);       \
    tot += lo16(aw##S##3) * __expf(trans[(i0 + 6) * KTAGS + STOP_TAG]);       \
    tot += hi16(aw##S##3) * __expf(trans[(i0 + 7) * KTAGS + STOP_TAG]);       \
    _Pragma("unroll")                                                         \
    for (int e = 0; e < 8; ++e) {                                             \
      const int kk = 32 + i0 + e;                                             \
      const int kc = kk < KTAGS ? kk : 0;                                     \
      float wv = (kk < KTAGS) ? __expf(trans[kc * KTAGS + STOP_TAG]) : 0.f;   \
      unsigned w = (e < 2) ? aw##S##4 : (e < 4) ? aw##S##5                    \
                 : (e < 6) ? aw##S##6 : aw##S##7;                             \
      float av = (e & 1) ? hi16(w) : lo16(w);                                 \
      tot += av * wv;                                                         \
    }                                                                         \
    tot += __shfl_xor(tot, 16);                                               \
    tot += __shfl_xor(tot, 32);                                               \
    tot = fmaxf(tot, 1e-35f);                                                 \
    const bool fin = (lenb > (cX) * SCHUNK) && (lenb <= ((cX) + 1) * SCHUNK); \
    if (l < 16 && fin)                                                        \
      rfin[(size_t)(b0 + l) * NCH + (cX)] = lacc##S + __logf(tot);            \
  }

__global__ __launch_bounds__(64, 1) void crf_chunk(
    const float* __restrict__ feats, const float* __restrict__ trans,
    const unsigned char* __restrict__ mask, int* __restrict__ lengths,
    float* __restrict__ rho, float* __restrict__ sigma,
    float* __restrict__ rfin) {
  const int bx = blockIdx.x;           // chunk pair: cA = bx, cB = bx + 32
  const int b0 = blockIdx.y * 16;      // batch group base
  const int l = threadIdx.x;
  const int g = l >> 4;                // 0..3
  const int bl = l & 15;               // batch-in-group
  const int i0 = 8 * g;                // per-lane k-base within a 32-slice
  const int cA = bx, cB = bx + NCH / 2;

  // ---- mask layout discriminator on byte-rows 0..1 (R8-proven).
  const uint4* m4u = reinterpret_cast<const uint4*>(mask);
  int bad = 0;
  #pragma unroll
  for (int r = 0; r < 2; ++r) {
    uint4 q = m4u[r * 64 + l];
    unsigned w[4] = {q.x, q.y, q.z, q.w};
    unsigned prevlast = 0xffu;
    #pragma unroll
    for (int k = 0; k < 4; ++k) {
      unsigned x = w[k];
      bad |= !(x == 0x01010101u || x == 0x00010101u || x == 0x00000101u ||
               x == 0x00000001u || x == 0u);
      if (k) bad |= (int)((prevlast == 0u) & ((x & 0xffu) != 0u));
      prevlast = x >> 24;
    }
    unsigned firstb = w[0] & 0xffu;
    unsigned pl = (unsigned)__shfl_up((int)prevlast, 1);
    bad |= (l == 0) ? (int)(firstb == 0u) : (int)((pl == 0u) & (firstb != 0u));
  }
  const bool is4byte = __any(bad);

  // ---- lengths: lane reads quarter g of mask row (b0+bl).
  int cnt = 0;
  if (!is4byte) {
    const uint4* mr = reinterpret_cast<const uint4*>(mask + (size_t)(b0 + bl) * TLEN);
    #pragma unroll
    for (int k = 0; k < 16; ++k) {
      uint4 q = mr[g * 16 + k];
      cnt += __popc(q.x) + __popc(q.y) + __popc(q.z) + __popc(q.w);
    }
  } else {
    const int4* mr = reinterpret_cast<const int4*>((const int*)mask + (size_t)(b0 + bl) * TLEN);
    for (int k = 0; k < 64; ++k) {
      int4 v = mr[g * 64 + k];
      cnt += (v.x != 0) + (v.y != 0) + (v.z != 0) + (v.w != 0);
    }
  }
  cnt += __shfl_xor(cnt, 16);
  cnt += __shfl_xor(cnt, 32);
  const int lenb = cnt;
  int ml = lenb;
  ml = max(ml, __shfl_xor(ml, 1));
  ml = max(ml, __shfl_xor(ml, 2));
  ml = max(ml, __shfl_xor(ml, 4));
  ml = max(ml, __shfl_xor(ml, 8));
  const int maxlen = ml;

  if (cA == 0 && l < 16) lengths[b0 + l] = lenb;
  if (cA != 0 && cA * SCHUNK >= maxlen) return;   // cB > cA also dead
  const bool actB = (cB * SCHUNK < maxlen);

  __shared__ __align__(16) unsigned eLds[8 * 64 * 4];
  __shared__ __align__(16) float slA[16 * SLS];
  __shared__ __align__(16) float slB[16 * SLS];

  // ---- C-layout probe: C[m][n] = 1+m via delta_k0 outer product.
  bool csw;
  {
    unsigned pa = pkbf((g == 0) ? (1.f + (float)bl) : 0.f, 0.f);
    unsigned pb = pkbf((g == 0) ? 1.f : 0.f, 0.f);
    f32x4 z = {0.f, 0.f, 0.f, 0.f};
    f32x4 p = __builtin_amdgcn_mfma_f32_16x16x32_bf16(
        frag4(pa, 0u, 0u, 0u), frag4(pb, 0u, 0u, 0u), z, 0, 0, 0);
    csw = (rdlane(p[1], 17) < 4.f);
  }

  // ---- build E fragments (R10-verbatim): k=32s+8g+2p+h, n=16nt+bl.
  #pragma unroll
  for (int s = 0; s < 2; ++s) {
    #pragma unroll
    for (int nt = 0; nt < 4; ++nt) {
      const int n = 16 * nt + bl;
      unsigned w[4];
      #pragma unroll
      for (int p = 0; p < 4; ++p) {
        const int k0 = 32 * s + i0 + 2 * p;
        float v0 = 0.f, v1 = 0.f;
        if (n < KTAGS) {
          if (k0 < KTAGS)     v0 = __expf(trans[k0 * KTAGS + n]);
          if (k0 + 1 < KTAGS) v1 = __expf(trans[(k0 + 1) * KTAGS + n]);
        }
        w[p] = pkbf(v0, v1);
      }
      *reinterpret_cast<uint4*>(&eLds[((s * 4 + nt) * 64 + l) * 4]) =
          make_uint4(w[0], w[1], w[2], w[3]);
    }
  }

  const int yo0 = (32 + i0 + 0 <= 48) ? (32 + i0 + 0) : 42;
  const int yo1 = (32 + i0 + 2 <= 48) ? (32 + i0 + 2) : 42;
  const int yo2 = (32 + i0 + 4 <= 48) ? (32 + i0 + 4) : 42;
  const int yo3 = (32 + i0 + 6 <= 48) ? (32 + i0 + 6) : 42;

  // ---- task parameters
  int tA0, nA, tB0 = 0, nB = 0;
  if (cA == 0) { tA0 = 1; nA = min(SCHUNK, maxlen) - 1; }
  else { tA0 = cA * SCHUNK - HALO; nA = HALO + min(SCHUNK, maxlen - cA * SCHUNK); }
  if (actB) { tB0 = cB * SCHUNK - HALO; nB = HALO + min(SCHUNK, maxlen - cB * SCHUNK); }

  // ---- state init
  float laccA, laccB = 0.f;
  unsigned awA0, awA1, awA2, awA3, awA4, awA5, awA6, awA7;
  unsigned awB0 = 0, awB1 = 0, awB2 = 0, awB3 = 0,
           awB4 = 0, awB5 = 0, awB6 = 0, awB7 = 0;
  INITSTATE(A, cA)
  if (actB) INITSTATE(B, cB)

  const uint4* eq = reinterpret_cast<const uint4*>(eLds);

  // ---- common interleaved loop, then tails
  const int kmin = nA < nB ? nA : nB;
  for (int k = 0; k < kmin; ++k) {
    const int tA = tA0 + k, tB = tB0 + k;
    STEP_LOAD(A, tA)
    STEP_LOAD(B, tB)
    STEP_MFMA(A)
    STEP_MFMA(B)
    STEP_POST(A, tA)
    STEP_POST(B, tB)
    if (k == HALO - 1 && l < 16) {
      if (cA != 0) rho[(size_t)(b0 + l) * NCH + cA] = laccA;
      rho[(size_t)(b0 + l) * NCH + cB] = laccB;
    }
  }
  for (int k = kmin; k < nA; ++k) {
    const int tA = tA0 + k;
    STEP_LOAD(A, tA)
    STEP_MFMA(A)
    STEP_POST(A, tA)
    if (k == HALO - 1 && cA != 0 && l < 16)
      rho[(size_t)(b0 + l) * NCH + cA] = laccA;
  }
  for (int k = kmin; k < nB; ++k) {
    const int tB = tB0 + k;
    STEP_LOAD(B, tB)
    STEP_MFMA(B)
    STEP_POST(B, tB)
    if (k == HALO - 1 && l < 16)
      rho[(size_t)(b0 + l) * NCH + cB] = laccB;
  }

  if (l < 16) {
    sigma[(size_t)(b0 + l) * NCH + cA] = laccA;
    if (actB) sigma[(size_t)(b0 + l) * NCH + cB] = laccB;
  }

  // ---- final-chunk STOP reductions
  STOPRED(A, cA)
  if (actB) STOPRED(B, cB)
}

// ---- combine: chain scalar offsets, pick final chunk's LSE, reduce over b.
__global__ __launch_bounds__(256) void crf_combine(const int* __restrict__ lengths,
                                                   const float* __restrict__ rho,
                                                   const float* __restrict__ sigma,
                                                   const float* __restrict__ rfin,
                                                   float* __restrict__ out) {
  const int b = threadIdx.x;
  const int len = lengths[b];
  const int nch = (len + SCHUNK - 1) / SCHUNK;
  float delta = 0.f;
  for (int c = 1; c < nch; ++c)
    delta += sigma[b * NCH + c - 1] - rho[b * NCH + c];
  float res = rfin[b * NCH + nch - 1] + delta;
  __shared__ float red[256];
  red[b] = res;
  __syncthreads();
  for (int s = 128; s > 0; s >>= 1) {
    if (b < s) red[b] += red[b + s];
    __syncthreads();
  }
  if (b == 0) out[0] = red[0];
}

extern "C" void kernel_launch(void* const* d_in, const int* in_sizes, int n_in,
                              void* d_out, int out_size, void* d_ws, size_t ws_size,
                              hipStream_t stream) {
  const float* feats = (const float*)d_in[0];
  const float* trans = (const float*)d_in[1];
  const unsigned char* mask = (const unsigned char*)d_in[2];
  float* out = (float*)d_out;

  int* lengths = (int*)d_ws;                 // 256 ints
  float* rho = (float*)(lengths + 256);      // B*NCH
  float* sigma = rho + NBATCH * NCH;         // B*NCH
  float* rfin = sigma + NBATCH * NCH;        // B*NCH

  dim3 grid(NCH / 2, NBATCH / 16);
  crf_chunk<<<grid, 64, 0, stream>>>(feats, trans, mask, lengths, rho, sigma, rfin);
  crf_combine<<<1, 256, 0, stream>>>(lengths, rho, sigma, rfin, out);
}